// Round 6
// baseline (497.296 us; speedup 1.0000x reference)
//
#include <hip/hip_runtime.h>
#include <hip/hip_bf16.h>

#define LEAKY(v) ((v) > 0.f ? (v) : 0.2f * (v))

__device__ __forceinline__ unsigned short f_to_bf16(float f) {
    union { float f; unsigned int i; } v; v.f = f;
    unsigned int x = v.i;
    return (unsigned short)((x + 0x7fffu + ((x >> 16) & 1u)) >> 16);
}

__device__ __forceinline__ float2 bf2_to_f2(unsigned int u) {
    union { unsigned int i; float f; } a, b;
    a.i = (u & 0xffffu) << 16;
    b.i = u & 0xffff0000u;
    float2 r; r.x = a.f; r.y = b.f;
    return r;
}

struct ConstBuf {
    float ws[3][4];      // dot(W[h,:], a_s[h,:])
    float wd[3][4];      // dot(W[h,:], a_d[h,:])
    float M[3][3][4];    // [branch][attr_k][head]
    float G[12][128];    // folded branch-W through Wf
    float bias2[128];    // bf + concat-bias through Wf
};
#define CB_FLOATS 1724   // 12+12+36+1536+128

struct BranchW { const float *W, *as_, *ad_, *ae, *We, *b; };
struct PreArgs { BranchW br[3]; const float *Wf, *bf; ConstBuf* cb; };

// ---------------- precompute folded weight constants (1 block) ----------------
__global__ void k_precompute(PreArgs A) {
    int t = threadIdx.x; // 256 threads
    if (t < 24) {
        int b = t / 8, r = t % 8, h = r & 3; bool isd = r >= 4;
        const float* a = isd ? A.br[b].ad_ : A.br[b].as_;
        float s = 0.f;
        for (int c = 0; c < 16; ++c) s += A.br[b].W[h * 16 + c] * a[h * 16 + c];
        if (isd) A.cb->wd[b][h] = s; else A.cb->ws[b][h] = s;
    }
    if (t >= 32 && t < 68) {
        int id = t - 32, b = id / 12, k = (id % 12) / 4, h = id & 3;
        float s = 0.f;
        for (int c = 0; c < 16; ++c) s += A.br[b].We[k * 64 + h * 16 + c] * A.br[b].ae[h * 16 + c];
        A.cb->M[b][k][h] = s;
    }
    if (t >= 128) {
        int j = t - 128;
        float s = A.bf[j];
        for (int b = 0; b < 3; ++b)
            for (int i = 0; i < 64; ++i)
                s += A.br[b].b[i] * A.Wf[(b * 64 + i) * 128 + j];
        A.cb->bias2[j] = s;
    }
    for (int id = t; id < 1536; id += 256) {
        int r = id >> 7, j = id & 127, b = r >> 2, h = r & 3;
        float s = 0.f;
        for (int c = 0; c < 16; ++c)
            s += A.br[b].W[h * 16 + c] * A.Wf[(b * 64 + h * 16 + c) * 128 + j];
        A.cb->G[r][j] = s;
    }
}

// ---------------- CSR build ----------------
__global__ void k_count(const int* __restrict__ ei, int E, int* __restrict__ deg) {
    int e = blockIdx.x * blockDim.x + threadIdx.x;
    if (e < E) atomicAdd(&deg[ei[E + e]], 1);
}

#define SCAN_EPB 2048

__global__ void k_scan1(const int* __restrict__ deg, int* __restrict__ off,
                        int* __restrict__ partials, int total) {
    __shared__ int sd[256];
    int t = threadIdx.x;
    int base = blockIdx.x * SCAN_EPB + t * 8;
    int v[8];
    int s = 0;
    #pragma unroll
    for (int i = 0; i < 8; ++i) {
        int idx = base + i;
        v[i] = (idx < total - 1) ? deg[idx] : 0;
        s += v[i];
    }
    sd[t] = s;
    __syncthreads();
    #pragma unroll
    for (int ofs = 1; ofs < 256; ofs <<= 1) {
        int u = (t >= ofs) ? sd[t - ofs] : 0;
        __syncthreads();
        sd[t] += u;
        __syncthreads();
    }
    if (t == 255) partials[blockIdx.x] = sd[255];
    int run = sd[t] - s;
    #pragma unroll
    for (int i = 0; i < 8; ++i) {
        int idx = base + i;
        if (idx < total) off[idx] = run;
        run += v[i];
    }
}

__global__ void k_scan2(int* __restrict__ partials, int nb) {
    __shared__ int sd[256];
    int t = threadIdx.x;
    int v = (t < nb) ? partials[t] : 0;
    sd[t] = v;
    __syncthreads();
    #pragma unroll
    for (int ofs = 1; ofs < 256; ofs <<= 1) {
        int u = (t >= ofs) ? sd[t - ofs] : 0;
        __syncthreads();
        sd[t] += u;
        __syncthreads();
    }
    if (t < nb) partials[t] = sd[t] - v;
}

__global__ void k_scan3(int* __restrict__ off, const int* __restrict__ partials,
                        int* __restrict__ cursor, int total) {
    int idx = blockIdx.x * blockDim.x + threadIdx.x;
    if (idx < total) {
        int v = off[idx] + partials[idx / SCAN_EPB];
        off[idx] = v;
        if (idx < total - 1) cursor[idx] = v;
    }
}

// scatter edges into CSR order: ONE 16B record per edge
// rec = (a0, a1, a2, bits{src | maskbits<<16})   [src < 2^16]
__global__ void k_scatter(const int* __restrict__ ei, const float* __restrict__ attr,
                          const int* __restrict__ mt, const int* __restrict__ mg,
                          const int* __restrict__ mp, int E, int* __restrict__ cursor,
                          float4* __restrict__ rec) {
    int e = blockIdx.x * blockDim.x + threadIdx.x;
    if (e < E) {
        int d = ei[E + e];
        int p = atomicAdd(&cursor[d], 1);
        float4 r;
        r.x = attr[e * 3 + 0];
        r.y = attr[e * 3 + 1];
        r.z = attr[e * 3 + 2];
        unsigned int bits = (mt[e] != 0 ? 1u : 0u) | (mg[e] != 0 ? 2u : 0u) | (mp[e] != 0 ? 4u : 0u);
        unsigned int packed = (unsigned int)ei[e] | (bits << 16);
        r.w = __int_as_float((int)packed);
        rec[p] = r;
    }
}

// ------- branch GATs + fusion layer: 16 lanes per node -> h1[N,128] ---------
// side-product: writes csr_src[p] (unpacked from rec) for the downstream gatagg
__global__ void k_branch(const float* __restrict__ x, const int* __restrict__ off,
                         const float4* __restrict__ rec, int* __restrict__ csr_src,
                         const ConstBuf* __restrict__ cb, float* __restrict__ h1, int N) {
    __shared__ float sc[CB_FLOATS]; // ws|wd|M (60), G (1536), bias2 (128)
    for (int i = threadIdx.x; i < CB_FLOATS; i += 256) sc[i] = ((const float*)cb)[i];
    __syncthreads();
    int g = threadIdx.x >> 4, l = threadIdx.x & 15;
    int n = blockIdx.x * 16 + g;
    if (n >= N) return;

    float num[12], den[12], asum[9], cnt[3];
    #pragma unroll
    for (int i = 0; i < 12; ++i) { num[i] = 0.f; den[i] = 0.f; }
    #pragma unroll
    for (int i = 0; i < 9; ++i) asum[i] = 0.f;
    cnt[0] = cnt[1] = cnt[2] = 0.f;

    float xn = x[n];
    int beg = off[n], end = off[n + 1];
    for (int p = beg + l; p < end; p += 16) {
        float4 r = rec[p];
        unsigned int packed = (unsigned int)__float_as_int(r.w);
        int src = (int)(packed & 0xffffu);
        unsigned int bits = packed >> 16;
        csr_src[p] = src;
        float xs = x[src];
        float a0 = r.x, a1 = r.y, a2 = r.z;
        #pragma unroll
        for (int b = 0; b < 3; ++b) {
            if ((bits >> b) & 1u) {
                cnt[b] += 1.f;
                asum[b * 3 + 0] += a0; asum[b * 3 + 1] += a1; asum[b * 3 + 2] += a2;
                #pragma unroll
                for (int h = 0; h < 4; ++h) {
                    float al = xs * sc[b * 4 + h] + xn * sc[12 + b * 4 + h]
                             + a0 * sc[24 + b * 12 + 0 + h]
                             + a1 * sc[24 + b * 12 + 4 + h]
                             + a2 * sc[24 + b * 12 + 8 + h];
                    al = LEAKY(al);
                    float ex = __expf(al);
                    den[b * 4 + h] += ex;
                    num[b * 4 + h] += ex * xs;
                }
            }
        }
    }
    // butterfly reduce over the 16-lane group (masks <16 stay in-group)
    #pragma unroll
    for (int m = 1; m < 16; m <<= 1) {
        #pragma unroll
        for (int i = 0; i < 12; ++i) {
            num[i] += __shfl_xor(num[i], m, 64);
            den[i] += __shfl_xor(den[i], m, 64);
        }
        #pragma unroll
        for (int i = 0; i < 9; ++i) asum[i] += __shfl_xor(asum[i], m, 64);
        #pragma unroll
        for (int i = 0; i < 3; ++i) cnt[i] += __shfl_xor(cnt[i], m, 64);
    }
    // per-node softmax epilogue (computed redundantly on all 16 lanes)
    float S[12];
    #pragma unroll
    for (int b = 0; b < 3; ++b) {
        float inv = 1.f / fmaxf(cnt[b], 1.f);
        float l0 = asum[b * 3 + 0] * inv, l1 = asum[b * 3 + 1] * inv, l2 = asum[b * 3 + 2] * inv;
        #pragma unroll
        for (int h = 0; h < 4; ++h) {
            float lp = xn * (sc[b * 4 + h] + sc[12 + b * 4 + h])
                     + l0 * sc[24 + b * 12 + 0 + h]
                     + l1 * sc[24 + b * 12 + 4 + h]
                     + l2 * sc[24 + b * 12 + 8 + h];
            lp = LEAKY(lp);
            float exl = __expf(lp);
            float sden = den[b * 4 + h] + exl;
            S[b * 4 + h] = (num[b * 4 + h] + exl * xn) / sden;
        }
    }
    // fused h1 = relu(S @ G + bias2): each lane -> 8 columns
    int jb = l * 8;
    float o[8];
    #pragma unroll
    for (int q = 0; q < 8; ++q) {
        int j = jb + q;
        float a = sc[60 + 1536 + j];
        #pragma unroll
        for (int k = 0; k < 12; ++k) a += S[k] * sc[60 + k * 128 + j];
        o[q] = fmaxf(a, 0.f);
    }
    float4* dst = (float4*)(h1 + (size_t)n * 128 + jb);
    dst[0] = make_float4(o[0], o[1], o[2], o[3]);
    dst[1] = make_float4(o[4], o[5], o[6], o[7]);
}

// ---- [N,128]@[128,128] -> bf16 hx table + fused attention scores ----
__global__ void k_mm128s(const float* __restrict__ A, const float* __restrict__ W,
                         const float* __restrict__ a_s, const float* __restrict__ a_d,
                         unsigned short* __restrict__ hxb, float* __restrict__ as_,
                         float* __restrict__ ad_, int N) {
    __shared__ float As[8 * 128];
    int j = threadIdx.x; // 128 threads
    int n0 = blockIdx.x * 8;
    #pragma unroll
    for (int i = 0; i < 8; ++i) {
        int n = n0 + i;
        As[i * 128 + j] = (n < N) ? A[(size_t)n * 128 + j] : 0.f;
    }
    __syncthreads();
    float acc[8] = {0.f, 0.f, 0.f, 0.f, 0.f, 0.f, 0.f, 0.f};
    const float4* As4 = (const float4*)As;
    for (int k = 0; k < 128; k += 4) {
        float w0 = W[(k + 0) * 128 + j];
        float w1 = W[(k + 1) * 128 + j];
        float w2 = W[(k + 2) * 128 + j];
        float w3 = W[(k + 3) * 128 + j];
        #pragma unroll
        for (int i = 0; i < 8; ++i) {
            float4 h4 = As4[(i * 128 + k) >> 2];
            acc[i] += h4.x * w0 + h4.y * w1 + h4.z * w2 + h4.w * w3;
        }
    }
    float asj = a_s[j], adj = a_d[j];
    int h = j >> 5;
    #pragma unroll
    for (int i = 0; i < 8; ++i) {
        int n = n0 + i;
        if (n < N) hxb[(size_t)n * 128 + j] = f_to_bf16(acc[i]);
        float vs = acc[i] * asj, vd = acc[i] * adj;
        #pragma unroll
        for (int m = 1; m < 32; m <<= 1) {
            vs += __shfl_xor(vs, m, 64);
            vd += __shfl_xor(vd, m, 64);
        }
        if ((j & 31) == 0 && n < N) {
            as_[(size_t)n * 4 + h] = vs;
            ad_[(size_t)n * 4 + h] = vd;
        }
    }
}

// ------- GAT aggregation (conv2/conv3): wave per node, bf16 rows, 8-wide MLP -
__global__ void k_gatagg(const unsigned short* __restrict__ hxb, const float* __restrict__ as_,
                         const float* __restrict__ ad_, const float* __restrict__ b,
                         const int* __restrict__ off, const int* __restrict__ csr_src,
                         float* __restrict__ out, int N) {
    int wave = threadIdx.x >> 6, lane = threadIdx.x & 63;
    int n = blockIdx.x * 4 + wave;
    if (n >= N) return;
    int h = lane >> 4;
    int lofs = lane * 2;
    float adn = ad_[(size_t)n * 4 + h];
    int beg = off[n], end = off[n + 1];
    float acc0 = 0.f, acc1 = 0.f, accd = 0.f;
    for (int p = beg; p < end; p += 8) {
        int s[8]; float e[8]; unsigned int u[8]; bool valid[8];
        #pragma unroll
        for (int i = 0; i < 8; ++i) {
            valid[i] = (p + i < end);
            int q = valid[i] ? (p + i) : beg;
            s[i] = csr_src[q];
        }
        #pragma unroll
        for (int i = 0; i < 8; ++i) e[i] = as_[(size_t)s[i] * 4 + h];
        #pragma unroll
        for (int i = 0; i < 8; ++i) u[i] = *(const unsigned int*)(hxb + (size_t)s[i] * 128 + lofs);
        #pragma unroll
        for (int i = 0; i < 8; ++i) {
            float ex = valid[i] ? __expf(LEAKY(e[i] + adn)) : 0.f;
            float2 v = bf2_to_f2(u[i]);
            acc0 += ex * v.x; acc1 += ex * v.y; accd += ex;
        }
    }
    float aln = LEAKY(as_[(size_t)n * 4 + h] + adn);
    float exl = __expf(aln);
    unsigned int un = *(const unsigned int*)(hxb + (size_t)n * 128 + lofs);
    float2 vn = bf2_to_f2(un);
    float inv = 1.f / (accd + exl);
    float o0 = (acc0 + exl * vn.x) * inv + b[lofs + 0];
    float o1 = (acc1 + exl * vn.y) * inv + b[lofs + 1];
    float2 r; r.x = fmaxf(o0, 0.f); r.y = fmaxf(o1, 0.f);
    *(float2*)(out + (size_t)n * 128 + lofs) = r;
}

// ------- classifier + log_softmax: wave = 8 nodes x 64 cols, Wc1 from L1 -----
#define CLS_NPB 32
__global__ void k_cls(const float* __restrict__ h3, const float* __restrict__ Wc1,
                      const float* __restrict__ bc1, const float* __restrict__ Wc2,
                      const float* __restrict__ bc2, float* __restrict__ out, int N) {
    __shared__ float hs[CLS_NPB * 128]; // 16 KB
    int tid = threadIdx.x;
    int nb = blockIdx.x * CLS_NPB;
    for (int i = tid; i < CLS_NPB * 128; i += 256) {
        int n = nb + (i >> 7);
        hs[i] = (n < N) ? h3[(size_t)n * 128 + (i & 127)] : 0.f;
    }
    __syncthreads();
    int g = tid >> 6, j = tid & 63; // wave g handles nodes nb+g*8 .. +7, lane j = hidden col
    const float4* hb4 = (const float4*)(hs + g * 8 * 128);
    float bj = bc1[j];
    float acc[8];
    #pragma unroll
    for (int i = 0; i < 8; ++i) acc[i] = bj;
    for (int k = 0; k < 128; k += 4) {
        float w0 = Wc1[(k + 0) * 64 + j];
        float w1 = Wc1[(k + 1) * 64 + j];
        float w2 = Wc1[(k + 2) * 64 + j];
        float w3 = Wc1[(k + 3) * 64 + j];
        #pragma unroll
        for (int i = 0; i < 8; ++i) {
            float4 h4 = hb4[(i * 128 + k) >> 2];
            acc[i] += h4.x * w0 + h4.y * w1 + h4.z * w2 + h4.w * w3;
        }
    }
    float w2v[5];
    #pragma unroll
    for (int c = 0; c < 5; ++c) w2v[c] = Wc2[j * 5 + c];
    #pragma unroll
    for (int i = 0; i < 8; ++i) {
        float t = fmaxf(acc[i], 0.f);
        float p[5];
        #pragma unroll
        for (int c = 0; c < 5; ++c) p[c] = t * w2v[c];
        #pragma unroll
        for (int m = 1; m < 64; m <<= 1) {
            #pragma unroll
            for (int c = 0; c < 5; ++c) p[c] += __shfl_xor(p[c], m, 64);
        }
        if (j == 0) {
            int n = nb + g * 8 + i;
            if (n < N) {
                float l[5], mx = -1e30f;
                #pragma unroll
                for (int c = 0; c < 5; ++c) { l[c] = p[c] + bc2[c]; mx = fmaxf(mx, l[c]); }
                float s = 0.f;
                #pragma unroll
                for (int c = 0; c < 5; ++c) s += __expf(l[c] - mx);
                float lse = mx + __logf(s);
                #pragma unroll
                for (int c = 0; c < 5; ++c) out[(size_t)n * 5 + c] = l[c] - lse;
            }
        }
    }
}

extern "C" void kernel_launch(void* const* d_in, const int* in_sizes, int n_in,
                              void* d_out, int out_size, void* d_ws, size_t ws_size,
                              hipStream_t stream) {
    const float* x    = (const float*)d_in[0];
    const int*   ei   = (const int*)d_in[1];
    const float* attr = (const float*)d_in[2];
    const int*   mt   = (const int*)d_in[3];
    const int*   mg   = (const int*)d_in[4];
    const int*   mp   = (const int*)d_in[5];
    const float* Wf   = (const float*)d_in[24];
    const float* bf   = (const float*)d_in[25];
    const float* W2   = (const float*)d_in[26];
    const float* a2s  = (const float*)d_in[27];
    const float* a2d  = (const float*)d_in[28];
    const float* b2   = (const float*)d_in[29];
    const float* W3   = (const float*)d_in[30];
    const float* a3s  = (const float*)d_in[31];
    const float* a3d  = (const float*)d_in[32];
    const float* b3   = (const float*)d_in[33];
    const float* Wc1  = (const float*)d_in[34];
    const float* bc1  = (const float*)d_in[35];
    const float* Wc2  = (const float*)d_in[36];
    const float* bc2  = (const float*)d_in[37];

    int N = in_sizes[0];
    int E = in_sizes[1] / 2;

    char* w = (char*)d_ws;
    auto alloc = [&](size_t bytes) {
        char* p = w;
        w += (bytes + 255) & ~(size_t)255;
        return p;
    };
    int* off      = (int*)alloc((size_t)(N + 1) * 4);
    int* cursor   = (int*)alloc((size_t)N * 4);
    int* deg      = (int*)alloc((size_t)N * 4);
    int* partials = (int*)alloc(1024 * 4);
    int* csr_src  = (int*)alloc((size_t)E * 4);
    ConstBuf* cb  = (ConstBuf*)alloc(sizeof(ConstBuf));
    float* as_    = (float*)alloc((size_t)N * 4 * 4);
    float* ad_    = (float*)alloc((size_t)N * 4 * 4);
    float* bufA   = (float*)alloc((size_t)N * 128 * 4);
    float4* rec   = (float4*)alloc((size_t)E * 16);
    unsigned short* hxb = (unsigned short*)alloc((size_t)N * 256);

    PreArgs pa;
    for (int b = 0; b < 3; ++b) {
        pa.br[b].W   = (const float*)d_in[6 + b * 6 + 0];
        pa.br[b].as_ = (const float*)d_in[6 + b * 6 + 1];
        pa.br[b].ad_ = (const float*)d_in[6 + b * 6 + 2];
        pa.br[b].ae  = (const float*)d_in[6 + b * 6 + 3];
        pa.br[b].We  = (const float*)d_in[6 + b * 6 + 4];
        pa.br[b].b   = (const float*)d_in[6 + b * 6 + 5];
    }
    pa.Wf = Wf; pa.bf = bf; pa.cb = cb;

    int total = N + 1;
    int nScanBlocks = (total + SCAN_EPB - 1) / SCAN_EPB;

    hipMemsetAsync(deg, 0, (size_t)N * 4, stream);
    hipLaunchKernelGGL(k_precompute, dim3(1), dim3(256), 0, stream, pa);
    int gE = (E + 255) / 256;
    hipLaunchKernelGGL(k_count, dim3(gE), dim3(256), 0, stream, ei, E, deg);
    hipLaunchKernelGGL(k_scan1, dim3(nScanBlocks), dim3(256), 0, stream, deg, off, partials, total);
    hipLaunchKernelGGL(k_scan2, dim3(1), dim3(256), 0, stream, partials, nScanBlocks);
    hipLaunchKernelGGL(k_scan3, dim3((total + 255) / 256), dim3(256), 0, stream,
                       off, partials, cursor, total);
    hipLaunchKernelGGL(k_scatter, dim3(gE), dim3(256), 0, stream,
                       ei, attr, mt, mg, mp, E, cursor, rec);
    hipLaunchKernelGGL(k_branch, dim3((N + 15) / 16), dim3(256), 0, stream,
                       x, off, rec, csr_src, cb, bufA, N);
    // conv2
    hipLaunchKernelGGL(k_mm128s, dim3((N + 7) / 8), dim3(128), 0, stream,
                       bufA, W2, a2s, a2d, hxb, as_, ad_, N);
    hipLaunchKernelGGL(k_gatagg, dim3((N + 3) / 4), dim3(256), 0, stream,
                       hxb, as_, ad_, b2, off, csr_src, bufA, N);
    // conv3
    hipLaunchKernelGGL(k_mm128s, dim3((N + 7) / 8), dim3(128), 0, stream,
                       bufA, W3, a3s, a3d, hxb, as_, ad_, N);
    hipLaunchKernelGGL(k_gatagg, dim3((N + 3) / 4), dim3(256), 0, stream,
                       hxb, as_, ad_, b3, off, csr_src, bufA, N);
    // classifier
    hipLaunchKernelGGL(k_cls, dim3((N + CLS_NPB - 1) / CLS_NPB), dim3(256), 0, stream,
                       bufA, Wc1, bc1, Wc2, bc2, (float*)d_out, N);
}

// Round 7
// 461.119 us; speedup vs baseline: 1.0785x; 1.0785x over previous
//
#include <hip/hip_runtime.h>
#include <hip/hip_bf16.h>

#define LEAKY(v) ((v) > 0.f ? (v) : 0.2f * (v))

typedef __attribute__((ext_vector_type(8))) short s8;          // 8 bf16 (4 VGPRs)
typedef __attribute__((ext_vector_type(4))) float f4;          // 4 fp32 acc
typedef __attribute__((ext_vector_type(4))) unsigned short us4;

__device__ __forceinline__ unsigned short f_to_bf16(float f) {
    union { float f; unsigned int i; } v; v.f = f;
    unsigned int x = v.i;
    return (unsigned short)((x + 0x7fffu + ((x >> 16) & 1u)) >> 16);
}

__device__ __forceinline__ float2 bf2_to_f2(unsigned int u) {
    union { unsigned int i; float f; } a, b;
    a.i = (u & 0xffffu) << 16;
    b.i = u & 0xffff0000u;
    float2 r; r.x = a.f; r.y = b.f;
    return r;
}

struct ConstBuf {
    float ws[3][4];      // dot(W[h,:], a_s[h,:])
    float wd[3][4];      // dot(W[h,:], a_d[h,:])
    float M[3][3][4];    // [branch][attr_k][head]
    float G[12][128];    // folded branch-W through Wf
    float bias2[128];    // bf + concat-bias through Wf
};
#define CB_FLOATS 1724   // 12+12+36+1536+128

struct BranchW { const float *W, *as_, *ad_, *ae, *We, *b; };
struct PreArgs { BranchW br[3]; const float *Wf, *bf; ConstBuf* cb; };

// ---------------- precompute folded weight constants (1 block) ----------------
__global__ void k_precompute(PreArgs A) {
    int t = threadIdx.x; // 256 threads
    if (t < 24) {
        int b = t / 8, r = t % 8, h = r & 3; bool isd = r >= 4;
        const float* a = isd ? A.br[b].ad_ : A.br[b].as_;
        float s = 0.f;
        for (int c = 0; c < 16; ++c) s += A.br[b].W[h * 16 + c] * a[h * 16 + c];
        if (isd) A.cb->wd[b][h] = s; else A.cb->ws[b][h] = s;
    }
    if (t >= 32 && t < 68) {
        int id = t - 32, b = id / 12, k = (id % 12) / 4, h = id & 3;
        float s = 0.f;
        for (int c = 0; c < 16; ++c) s += A.br[b].We[k * 64 + h * 16 + c] * A.br[b].ae[h * 16 + c];
        A.cb->M[b][k][h] = s;
    }
    if (t >= 128) {
        int j = t - 128;
        float s = A.bf[j];
        for (int b = 0; b < 3; ++b)
            for (int i = 0; i < 64; ++i)
                s += A.br[b].b[i] * A.Wf[(b * 64 + i) * 128 + j];
        A.cb->bias2[j] = s;
    }
    for (int id = t; id < 1536; id += 256) {
        int r = id >> 7, j = id & 127, b = r >> 2, h = r & 3;
        float s = 0.f;
        for (int c = 0; c < 16; ++c)
            s += A.br[b].W[h * 16 + c] * A.Wf[(b * 64 + h * 16 + c) * 128 + j];
        A.cb->G[r][j] = s;
    }
}

// ---- pre-swizzle W[128][128] fp32 -> bf16 MFMA B-fragment layout ----
// out[((ct*4+kk)*64 + lane)*8 + j] = bf16(W[(kk*32 + (lane>>4)*8 + j)*128 + ct*16 + (lane&15)])
__global__ void k_prepw(const float* __restrict__ W, unsigned short* __restrict__ out) {
    for (int i = threadIdx.x; i < 16384; i += 256) {
        int j = i & 7, lane = (i >> 3) & 63, kk = (i >> 9) & 3, ct = i >> 11;
        int k = kk * 32 + (lane >> 4) * 8 + j;
        int n = ct * 16 + (lane & 15);
        out[i] = f_to_bf16(W[k * 128 + n]);
    }
}

// ---------------- CSR build ----------------
__global__ void k_count(const int* __restrict__ ei, int E, int* __restrict__ deg) {
    int e = blockIdx.x * blockDim.x + threadIdx.x;
    if (e < E) atomicAdd(&deg[ei[E + e]], 1);
}

#define SCAN_EPB 2048

__global__ void k_scan1(const int* __restrict__ deg, int* __restrict__ off,
                        int* __restrict__ partials, int total) {
    __shared__ int sd[256];
    int t = threadIdx.x;
    int base = blockIdx.x * SCAN_EPB + t * 8;
    int v[8];
    int s = 0;
    #pragma unroll
    for (int i = 0; i < 8; ++i) {
        int idx = base + i;
        v[i] = (idx < total - 1) ? deg[idx] : 0;
        s += v[i];
    }
    sd[t] = s;
    __syncthreads();
    #pragma unroll
    for (int ofs = 1; ofs < 256; ofs <<= 1) {
        int u = (t >= ofs) ? sd[t - ofs] : 0;
        __syncthreads();
        sd[t] += u;
        __syncthreads();
    }
    if (t == 255) partials[blockIdx.x] = sd[255];
    int run = sd[t] - s;
    #pragma unroll
    for (int i = 0; i < 8; ++i) {
        int idx = base + i;
        if (idx < total) off[idx] = run;
        run += v[i];
    }
}

__global__ void k_scan2(int* __restrict__ partials, int nb) {
    __shared__ int sd[256];
    int t = threadIdx.x;
    int v = (t < nb) ? partials[t] : 0;
    sd[t] = v;
    __syncthreads();
    #pragma unroll
    for (int ofs = 1; ofs < 256; ofs <<= 1) {
        int u = (t >= ofs) ? sd[t - ofs] : 0;
        __syncthreads();
        sd[t] += u;
        __syncthreads();
    }
    if (t < nb) partials[t] = sd[t] - v;
}

__global__ void k_scan3(int* __restrict__ off, const int* __restrict__ partials,
                        int* __restrict__ cursor, int total) {
    int idx = blockIdx.x * blockDim.x + threadIdx.x;
    if (idx < total) {
        int v = off[idx] + partials[idx / SCAN_EPB];
        off[idx] = v;
        if (idx < total - 1) cursor[idx] = v;
    }
}

// scatter edges into CSR order: ONE 16B record per edge
// rec = (a0, a1, a2, bits{src | maskbits<<16})   [src < 2^16]
__global__ void k_scatter(const int* __restrict__ ei, const float* __restrict__ attr,
                          const int* __restrict__ mt, const int* __restrict__ mg,
                          const int* __restrict__ mp, int E, int* __restrict__ cursor,
                          float4* __restrict__ rec) {
    int e = blockIdx.x * blockDim.x + threadIdx.x;
    if (e < E) {
        int d = ei[E + e];
        int p = atomicAdd(&cursor[d], 1);
        float4 r;
        r.x = attr[e * 3 + 0];
        r.y = attr[e * 3 + 1];
        r.z = attr[e * 3 + 2];
        unsigned int bits = (mt[e] != 0 ? 1u : 0u) | (mg[e] != 0 ? 2u : 0u) | (mp[e] != 0 ? 4u : 0u);
        unsigned int packed = (unsigned int)ei[e] | (bits << 16);
        r.w = __int_as_float((int)packed);
        rec[p] = r;
    }
}

// ------- branch GATs + fusion layer: 16 lanes per node -> h1[N,128] ---------
// side-product: writes csr_src[p] (unpacked from rec) for the downstream gatagg
__global__ void k_branch(const float* __restrict__ x, const int* __restrict__ off,
                         const float4* __restrict__ rec, int* __restrict__ csr_src,
                         const ConstBuf* __restrict__ cb, float* __restrict__ h1, int N) {
    __shared__ float sc[CB_FLOATS]; // ws|wd|M (60), G (1536), bias2 (128)
    for (int i = threadIdx.x; i < CB_FLOATS; i += 256) sc[i] = ((const float*)cb)[i];
    __syncthreads();
    int g = threadIdx.x >> 4, l = threadIdx.x & 15;
    int n = blockIdx.x * 16 + g;
    if (n >= N) return;

    float num[12], den[12], asum[9], cnt[3];
    #pragma unroll
    for (int i = 0; i < 12; ++i) { num[i] = 0.f; den[i] = 0.f; }
    #pragma unroll
    for (int i = 0; i < 9; ++i) asum[i] = 0.f;
    cnt[0] = cnt[1] = cnt[2] = 0.f;

    float xn = x[n];
    int beg = off[n], end = off[n + 1];
    for (int p = beg + l; p < end; p += 16) {
        float4 r = rec[p];
        unsigned int packed = (unsigned int)__float_as_int(r.w);
        int src = (int)(packed & 0xffffu);
        unsigned int bits = packed >> 16;
        csr_src[p] = src;
        float xs = x[src];
        float a0 = r.x, a1 = r.y, a2 = r.z;
        #pragma unroll
        for (int b = 0; b < 3; ++b) {
            if ((bits >> b) & 1u) {
                cnt[b] += 1.f;
                asum[b * 3 + 0] += a0; asum[b * 3 + 1] += a1; asum[b * 3 + 2] += a2;
                #pragma unroll
                for (int h = 0; h < 4; ++h) {
                    float al = xs * sc[b * 4 + h] + xn * sc[12 + b * 4 + h]
                             + a0 * sc[24 + b * 12 + 0 + h]
                             + a1 * sc[24 + b * 12 + 4 + h]
                             + a2 * sc[24 + b * 12 + 8 + h];
                    al = LEAKY(al);
                    float ex = __expf(al);
                    den[b * 4 + h] += ex;
                    num[b * 4 + h] += ex * xs;
                }
            }
        }
    }
    // butterfly reduce over the 16-lane group (masks <16 stay in-group)
    #pragma unroll
    for (int m = 1; m < 16; m <<= 1) {
        #pragma unroll
        for (int i = 0; i < 12; ++i) {
            num[i] += __shfl_xor(num[i], m, 64);
            den[i] += __shfl_xor(den[i], m, 64);
        }
        #pragma unroll
        for (int i = 0; i < 9; ++i) asum[i] += __shfl_xor(asum[i], m, 64);
        #pragma unroll
        for (int i = 0; i < 3; ++i) cnt[i] += __shfl_xor(cnt[i], m, 64);
    }
    // per-node softmax epilogue (computed redundantly on all 16 lanes)
    float S[12];
    #pragma unroll
    for (int b = 0; b < 3; ++b) {
        float inv = 1.f / fmaxf(cnt[b], 1.f);
        float l0 = asum[b * 3 + 0] * inv, l1 = asum[b * 3 + 1] * inv, l2 = asum[b * 3 + 2] * inv;
        #pragma unroll
        for (int h = 0; h < 4; ++h) {
            float lp = xn * (sc[b * 4 + h] + sc[12 + b * 4 + h])
                     + l0 * sc[24 + b * 12 + 0 + h]
                     + l1 * sc[24 + b * 12 + 4 + h]
                     + l2 * sc[24 + b * 12 + 8 + h];
            lp = LEAKY(lp);
            float exl = __expf(lp);
            float sden = den[b * 4 + h] + exl;
            S[b * 4 + h] = (num[b * 4 + h] + exl * xn) / sden;
        }
    }
    // fused h1 = relu(S @ G + bias2): each lane -> 8 columns
    int jb = l * 8;
    float o[8];
    #pragma unroll
    for (int q = 0; q < 8; ++q) {
        int j = jb + q;
        float a = sc[60 + 1536 + j];
        #pragma unroll
        for (int k = 0; k < 12; ++k) a += S[k] * sc[60 + k * 128 + j];
        o[q] = fmaxf(a, 0.f);
    }
    float4* dst = (float4*)(h1 + (size_t)n * 128 + jb);
    dst[0] = make_float4(o[0], o[1], o[2], o[3]);
    dst[1] = make_float4(o[4], o[5], o[6], o[7]);
}

// ---- MFMA [N,128]@[128,128]: A fp32 -> bf16, W pre-swizzled frags -> bf16 hx ----
// 256 threads = 4 waves; 64 nodes/block; wave w owns rows w*16..w*16+15.
__global__ void k_mm128b(const float* __restrict__ A, const unsigned short* __restrict__ wf,
                         unsigned short* __restrict__ hxb, int N) {
    __shared__ unsigned short sA[64 * 136]; // 272B padded rows -> conflict-free frag reads
    __shared__ unsigned short sW[16384];    // 32 KB fragment-layout W
    int tid = threadIdx.x;
    int base = blockIdx.x * 64;
    // stage W frags (coalesced 16B chunks)
    const float4* wf4 = (const float4*)wf;
    float4* sW4 = (float4*)sW;
    #pragma unroll
    for (int i = 0; i < 8; ++i) sW4[tid + i * 256] = wf4[tid + i * 256];
    // stage A rows as bf16 (coalesced float4 global reads)
    #pragma unroll
    for (int i = 0; i < 8; ++i) {
        int f = tid + i * 256;            // float4 index into 64x128 tile
        int row = f >> 5, c4 = f & 31;
        int n = base + row;
        float4 v = (n < N) ? ((const float4*)A)[(size_t)n * 32 + c4]
                           : make_float4(0.f, 0.f, 0.f, 0.f);
        us4 b;
        b.x = f_to_bf16(v.x); b.y = f_to_bf16(v.y);
        b.z = f_to_bf16(v.z); b.w = f_to_bf16(v.w);
        *(us4*)(&sA[row * 136 + c4 * 4]) = b;
    }
    __syncthreads();
    int wv = tid >> 6, lane = tid & 63;
    int q = lane >> 4, l15 = lane & 15;
    int rowbase = wv * 16;
    // A-frags: lane holds A[m=l15][k=q*8+j] per K-step
    s8 af[4];
    #pragma unroll
    for (int kk = 0; kk < 4; ++kk)
        af[kk] = *(const s8*)(&sA[(rowbase + l15) * 136 + kk * 32 + q * 8]);
    #pragma unroll
    for (int ct = 0; ct < 8; ++ct) {
        f4 acc = {0.f, 0.f, 0.f, 0.f};
        #pragma unroll
        for (int kk = 0; kk < 4; ++kk) {
            s8 bfr = *(const s8*)(&sW[((ct * 4 + kk) * 64 + lane) * 8]);
            acc = __builtin_amdgcn_mfma_f32_16x16x32_bf16(af[kk], bfr, acc, 0, 0, 0);
        }
        // D[row=q*4+r][col=l15] per verified C/D layout
        #pragma unroll
        for (int r = 0; r < 4; ++r) {
            int n = base + rowbase + q * 4 + r;
            if (n < N) hxb[(size_t)n * 128 + ct * 16 + l15] = f_to_bf16(acc[r]);
        }
    }
}

// ---- attention scores from bf16 hx table ----
__global__ void k_scoresb(const unsigned short* __restrict__ hxb, const float* __restrict__ a_s,
                          const float* __restrict__ a_d, float* __restrict__ as_,
                          float* __restrict__ ad_, int N) {
    __shared__ float sas[128], sad[128];
    if (threadIdx.x < 128) { sas[threadIdx.x] = a_s[threadIdx.x]; sad[threadIdx.x] = a_d[threadIdx.x]; }
    __syncthreads();
    int tid = blockIdx.x * blockDim.x + threadIdx.x;
    int n = tid >> 2, h = tid & 3;
    if (n >= N) return;
    const uint4* r4 = (const uint4*)(hxb + (size_t)n * 128 + h * 32);
    float ss = 0.f, sd2 = 0.f;
    #pragma unroll
    for (int c = 0; c < 4; ++c) {
        uint4 blob = r4[c];
        unsigned int us[4] = { blob.x, blob.y, blob.z, blob.w };
        #pragma unroll
        for (int q = 0; q < 4; ++q) {
            float2 v = bf2_to_f2(us[q]);
            int col = h * 32 + c * 8 + q * 2;
            ss  += v.x * sas[col] + v.y * sas[col + 1];
            sd2 += v.x * sad[col] + v.y * sad[col + 1];
        }
    }
    as_[(size_t)n * 4 + h] = ss;
    ad_[(size_t)n * 4 + h] = sd2;
}

// ------- GAT aggregation (conv2/conv3): wave per node, bf16 rows, 8-wide MLP -
__global__ void k_gatagg(const unsigned short* __restrict__ hxb, const float* __restrict__ as_,
                         const float* __restrict__ ad_, const float* __restrict__ b,
                         const int* __restrict__ off, const int* __restrict__ csr_src,
                         float* __restrict__ out, int N) {
    int wave = threadIdx.x >> 6, lane = threadIdx.x & 63;
    int n = blockIdx.x * 4 + wave;
    if (n >= N) return;
    int h = lane >> 4;
    int lofs = lane * 2;
    float adn = ad_[(size_t)n * 4 + h];
    int beg = off[n], end = off[n + 1];
    float acc0 = 0.f, acc1 = 0.f, accd = 0.f;
    for (int p = beg; p < end; p += 8) {
        int s[8]; float e[8]; unsigned int u[8]; bool valid[8];
        #pragma unroll
        for (int i = 0; i < 8; ++i) {
            valid[i] = (p + i < end);
            int q = valid[i] ? (p + i) : beg;
            s[i] = csr_src[q];
        }
        #pragma unroll
        for (int i = 0; i < 8; ++i) e[i] = as_[(size_t)s[i] * 4 + h];
        #pragma unroll
        for (int i = 0; i < 8; ++i) u[i] = *(const unsigned int*)(hxb + (size_t)s[i] * 128 + lofs);
        #pragma unroll
        for (int i = 0; i < 8; ++i) {
            float ex = valid[i] ? __expf(LEAKY(e[i] + adn)) : 0.f;
            float2 v = bf2_to_f2(u[i]);
            acc0 += ex * v.x; acc1 += ex * v.y; accd += ex;
        }
    }
    float aln = LEAKY(as_[(size_t)n * 4 + h] + adn);
    float exl = __expf(aln);
    unsigned int un = *(const unsigned int*)(hxb + (size_t)n * 128 + lofs);
    float2 vn = bf2_to_f2(un);
    float inv = 1.f / (accd + exl);
    float o0 = (acc0 + exl * vn.x) * inv + b[lofs + 0];
    float o1 = (acc1 + exl * vn.y) * inv + b[lofs + 1];
    float2 r; r.x = fmaxf(o0, 0.f); r.y = fmaxf(o1, 0.f);
    *(float2*)(out + (size_t)n * 128 + lofs) = r;
}

// ------- classifier + log_softmax: wave = 8 nodes x 64 cols, Wc1 from L1 -----
#define CLS_NPB 32
__global__ void k_cls(const float* __restrict__ h3, const float* __restrict__ Wc1,
                      const float* __restrict__ bc1, const float* __restrict__ Wc2,
                      const float* __restrict__ bc2, float* __restrict__ out, int N) {
    __shared__ float hs[CLS_NPB * 128]; // 16 KB
    int tid = threadIdx.x;
    int nb = blockIdx.x * CLS_NPB;
    for (int i = tid; i < CLS_NPB * 128; i += 256) {
        int n = nb + (i >> 7);
        hs[i] = (n < N) ? h3[(size_t)n * 128 + (i & 127)] : 0.f;
    }
    __syncthreads();
    int g = tid >> 6, j = tid & 63;
    const float4* hb4 = (const float4*)(hs + g * 8 * 128);
    float bj = bc1[j];
    float acc[8];
    #pragma unroll
    for (int i = 0; i < 8; ++i) acc[i] = bj;
    for (int k = 0; k < 128; k += 4) {
        float w0 = Wc1[(k + 0) * 64 + j];
        float w1 = Wc1[(k + 1) * 64 + j];
        float w2 = Wc1[(k + 2) * 64 + j];
        float w3 = Wc1[(k + 3) * 64 + j];
        #pragma unroll
        for (int i = 0; i < 8; ++i) {
            float4 h4 = hb4[(i * 128 + k) >> 2];
            acc[i] += h4.x * w0 + h4.y * w1 + h4.z * w2 + h4.w * w3;
        }
    }
    float w2v[5];
    #pragma unroll
    for (int c = 0; c < 5; ++c) w2v[c] = Wc2[j * 5 + c];
    #pragma unroll
    for (int i = 0; i < 8; ++i) {
        float t = fmaxf(acc[i], 0.f);
        float p[5];
        #pragma unroll
        for (int c = 0; c < 5; ++c) p[c] = t * w2v[c];
        #pragma unroll
        for (int m = 1; m < 64; m <<= 1) {
            #pragma unroll
            for (int c = 0; c < 5; ++c) p[c] += __shfl_xor(p[c], m, 64);
        }
        if (j == 0) {
            int n = nb + g * 8 + i;
            if (n < N) {
                float l[5], mx = -1e30f;
                #pragma unroll
                for (int c = 0; c < 5; ++c) { l[c] = p[c] + bc2[c]; mx = fmaxf(mx, l[c]); }
                float s = 0.f;
                #pragma unroll
                for (int c = 0; c < 5; ++c) s += __expf(l[c] - mx);
                float lse = mx + __logf(s);
                #pragma unroll
                for (int c = 0; c < 5; ++c) out[(size_t)n * 5 + c] = l[c] - lse;
            }
        }
    }
}

extern "C" void kernel_launch(void* const* d_in, const int* in_sizes, int n_in,
                              void* d_out, int out_size, void* d_ws, size_t ws_size,
                              hipStream_t stream) {
    const float* x    = (const float*)d_in[0];
    const int*   ei   = (const int*)d_in[1];
    const float* attr = (const float*)d_in[2];
    const int*   mt   = (const int*)d_in[3];
    const int*   mg   = (const int*)d_in[4];
    const int*   mp   = (const int*)d_in[5];
    const float* Wf   = (const float*)d_in[24];
    const float* bf   = (const float*)d_in[25];
    const float* W2   = (const float*)d_in[26];
    const float* a2s  = (const float*)d_in[27];
    const float* a2d  = (const float*)d_in[28];
    const float* b2   = (const float*)d_in[29];
    const float* W3   = (const float*)d_in[30];
    const float* a3s  = (const float*)d_in[31];
    const float* a3d  = (const float*)d_in[32];
    const float* b3   = (const float*)d_in[33];
    const float* Wc1  = (const float*)d_in[34];
    const float* bc1  = (const float*)d_in[35];
    const float* Wc2  = (const float*)d_in[36];
    const float* bc2  = (const float*)d_in[37];

    int N = in_sizes[0];
    int E = in_sizes[1] / 2;

    char* w = (char*)d_ws;
    auto alloc = [&](size_t bytes) {
        char* p = w;
        w += (bytes + 255) & ~(size_t)255;
        return p;
    };
    int* off      = (int*)alloc((size_t)(N + 1) * 4);
    int* cursor   = (int*)alloc((size_t)N * 4);
    int* deg      = (int*)alloc((size_t)N * 4);
    int* partials = (int*)alloc(1024 * 4);
    int* csr_src  = (int*)alloc((size_t)E * 4);
    ConstBuf* cb  = (ConstBuf*)alloc(sizeof(ConstBuf));
    float* as_    = (float*)alloc((size_t)N * 4 * 4);
    float* ad_    = (float*)alloc((size_t)N * 4 * 4);
    float* bufA   = (float*)alloc((size_t)N * 128 * 4);
    float4* rec   = (float4*)alloc((size_t)E * 16);
    unsigned short* hxb = (unsigned short*)alloc((size_t)N * 256);
    unsigned short* wf2 = (unsigned short*)alloc(16384 * 2);
    unsigned short* wf3 = (unsigned short*)alloc(16384 * 2);

    PreArgs pa;
    for (int b = 0; b < 3; ++b) {
        pa.br[b].W   = (const float*)d_in[6 + b * 6 + 0];
        pa.br[b].as_ = (const float*)d_in[6 + b * 6 + 1];
        pa.br[b].ad_ = (const float*)d_in[6 + b * 6 + 2];
        pa.br[b].ae  = (const float*)d_in[6 + b * 6 + 3];
        pa.br[b].We  = (const float*)d_in[6 + b * 6 + 4];
        pa.br[b].b   = (const float*)d_in[6 + b * 6 + 5];
    }
    pa.Wf = Wf; pa.bf = bf; pa.cb = cb;

    int total = N + 1;
    int nScanBlocks = (total + SCAN_EPB - 1) / SCAN_EPB;

    hipMemsetAsync(deg, 0, (size_t)N * 4, stream);
    hipLaunchKernelGGL(k_precompute, dim3(1), dim3(256), 0, stream, pa);
    hipLaunchKernelGGL(k_prepw, dim3(1), dim3(256), 0, stream, W2, wf2);
    hipLaunchKernelGGL(k_prepw, dim3(1), dim3(256), 0, stream, W3, wf3);
    int gE = (E + 255) / 256;
    hipLaunchKernelGGL(k_count, dim3(gE), dim3(256), 0, stream, ei, E, deg);
    hipLaunchKernelGGL(k_scan1, dim3(nScanBlocks), dim3(256), 0, stream, deg, off, partials, total);
    hipLaunchKernelGGL(k_scan2, dim3(1), dim3(256), 0, stream, partials, nScanBlocks);
    hipLaunchKernelGGL(k_scan3, dim3((total + 255) / 256), dim3(256), 0, stream,
                       off, partials, cursor, total);
    hipLaunchKernelGGL(k_scatter, dim3(gE), dim3(256), 0, stream,
                       ei, attr, mt, mg, mp, E, cursor, rec);
    hipLaunchKernelGGL(k_branch, dim3((N + 15) / 16), dim3(256), 0, stream,
                       x, off, rec, csr_src, cb, bufA, N);
    // conv2
    hipLaunchKernelGGL(k_mm128b, dim3((N + 63) / 64), dim3(256), 0, stream,
                       bufA, wf2, hxb, N);
    hipLaunchKernelGGL(k_scoresb, dim3(((size_t)N * 4 + 255) / 256), dim3(256), 0, stream,
                       hxb, a2s, a2d, as_, ad_, N);
    hipLaunchKernelGGL(k_gatagg, dim3((N + 3) / 4), dim3(256), 0, stream,
                       hxb, as_, ad_, b2, off, csr_src, bufA, N);
    // conv3
    hipLaunchKernelGGL(k_mm128b, dim3((N + 63) / 64), dim3(256), 0, stream,
                       bufA, wf3, hxb, N);
    hipLaunchKernelGGL(k_scoresb, dim3(((size_t)N * 4 + 255) / 256), dim3(256), 0, stream,
                       hxb, a3s, a3d, as_, ad_, N);
    hipLaunchKernelGGL(k_gatagg, dim3((N + 3) / 4), dim3(256), 0, stream,
                       hxb, as_, ad_, b3, off, csr_src, bufA, N);
    // classifier
    hipLaunchKernelGGL(k_cls, dim3((N + CLS_NPB - 1) / CLS_NPB), dim3(256), 0, stream,
                       bufA, Wc1, bc1, Wc2, bc2, (float*)d_out, N);
}

// Round 8
// 451.672 us; speedup vs baseline: 1.1010x; 1.0209x over previous
//
#include <hip/hip_runtime.h>
#include <hip/hip_bf16.h>

#define LEAKY(v) ((v) > 0.f ? (v) : 0.2f * (v))

typedef __attribute__((ext_vector_type(8))) short s8;          // 8 bf16 (4 VGPRs)
typedef __attribute__((ext_vector_type(4))) float f4;          // 4 fp32 acc
typedef __attribute__((ext_vector_type(4))) unsigned short us4;

__device__ __forceinline__ unsigned short f_to_bf16(float f) {
    union { float f; unsigned int i; } v; v.f = f;
    unsigned int x = v.i;
    return (unsigned short)((x + 0x7fffu + ((x >> 16) & 1u)) >> 16);
}

__device__ __forceinline__ float2 bf2_to_f2(unsigned int u) {
    union { unsigned int i; float f; } a, b;
    a.i = (u & 0xffffu) << 16;
    b.i = u & 0xffff0000u;
    float2 r; r.x = a.f; r.y = b.f;
    return r;
}

struct ConstBuf {
    float ws[3][4];      // dot(W[h,:], a_s[h,:])
    float wd[3][4];      // dot(W[h,:], a_d[h,:])
    float M[3][3][4];    // [branch][attr_k][head]
    float G[12][128];    // folded branch-W through Wf
    float bias2[128];    // bf + concat-bias through Wf
};
#define CB_FLOATS 1724   // 12+12+36+1536+128

struct BranchW { const float *W, *as_, *ad_, *ae, *We, *b; };
struct PreArgs { BranchW br[3]; const float *Wf, *bf; ConstBuf* cb; };

// --- fused precompute: block 0 = folded consts; blocks 1,2 = W2/W3 swizzle ---
__global__ void k_pre_all(PreArgs A, const float* __restrict__ W2, unsigned short* __restrict__ wf2,
                          const float* __restrict__ W3, unsigned short* __restrict__ wf3) {
    int t = threadIdx.x; // 256 threads
    if (blockIdx.x == 0) {
        if (t < 24) {
            int b = t / 8, r = t % 8, h = r & 3; bool isd = r >= 4;
            const float* a = isd ? A.br[b].ad_ : A.br[b].as_;
            float s = 0.f;
            for (int c = 0; c < 16; ++c) s += A.br[b].W[h * 16 + c] * a[h * 16 + c];
            if (isd) A.cb->wd[b][h] = s; else A.cb->ws[b][h] = s;
        }
        if (t >= 32 && t < 68) {
            int id = t - 32, b = id / 12, k = (id % 12) / 4, h = id & 3;
            float s = 0.f;
            for (int c = 0; c < 16; ++c) s += A.br[b].We[k * 64 + h * 16 + c] * A.br[b].ae[h * 16 + c];
            A.cb->M[b][k][h] = s;
        }
        if (t >= 128) {
            int j = t - 128;
            float s = A.bf[j];
            for (int b = 0; b < 3; ++b)
                for (int i = 0; i < 64; ++i)
                    s += A.br[b].b[i] * A.Wf[(b * 64 + i) * 128 + j];
            A.cb->bias2[j] = s;
        }
        for (int id = t; id < 1536; id += 256) {
            int r = id >> 7, j = id & 127, b = r >> 2, h = r & 3;
            float s = 0.f;
            for (int c = 0; c < 16; ++c)
                s += A.br[b].W[h * 16 + c] * A.Wf[(b * 64 + h * 16 + c) * 128 + j];
            A.cb->G[r][j] = s;
        }
    } else {
        const float* W = (blockIdx.x == 1) ? W2 : W3;
        unsigned short* out = (blockIdx.x == 1) ? wf2 : wf3;
        for (int i = t; i < 16384; i += 256) {
            int j = i & 7, lane = (i >> 3) & 63, kk = (i >> 9) & 3, ct = i >> 11;
            int k = kk * 32 + (lane >> 4) * 8 + j;
            int n = ct * 16 + (lane & 15);
            out[i] = f_to_bf16(W[k * 128 + n]);
        }
    }
}

// ---------------- CSR build ----------------
__global__ void k_count(const int* __restrict__ ei, int E, int* __restrict__ deg) {
    int base = (blockIdx.x * blockDim.x + threadIdx.x) * 4;
    if (base >= E) return;
    if (base + 3 < E && (E & 3) == 0) {
        int4 d = *(const int4*)(ei + E + base);
        atomicAdd(&deg[d.x], 1);
        atomicAdd(&deg[d.y], 1);
        atomicAdd(&deg[d.z], 1);
        atomicAdd(&deg[d.w], 1);
    } else {
        for (int e = base; e < E && e < base + 4; ++e) atomicAdd(&deg[ei[E + e]], 1);
    }
}

#define SCAN_EPB 2048

__global__ void k_scan1(const int* __restrict__ deg, int* __restrict__ off,
                        int* __restrict__ partials, int total) {
    __shared__ int sd[256];
    int t = threadIdx.x;
    int base = blockIdx.x * SCAN_EPB + t * 8;
    int v[8];
    int s = 0;
    #pragma unroll
    for (int i = 0; i < 8; ++i) {
        int idx = base + i;
        v[i] = (idx < total - 1) ? deg[idx] : 0;
        s += v[i];
    }
    sd[t] = s;
    __syncthreads();
    #pragma unroll
    for (int ofs = 1; ofs < 256; ofs <<= 1) {
        int u = (t >= ofs) ? sd[t - ofs] : 0;
        __syncthreads();
        sd[t] += u;
        __syncthreads();
    }
    if (t == 255) partials[blockIdx.x] = sd[255];
    int run = sd[t] - s;
    #pragma unroll
    for (int i = 0; i < 8; ++i) {
        int idx = base + i;
        if (idx < total) off[idx] = run;
        run += v[i];
    }
}

__global__ void k_scan2(int* __restrict__ partials, int nb) {
    __shared__ int sd[256];
    int t = threadIdx.x;
    int v = (t < nb) ? partials[t] : 0;
    sd[t] = v;
    __syncthreads();
    #pragma unroll
    for (int ofs = 1; ofs < 256; ofs <<= 1) {
        int u = (t >= ofs) ? sd[t - ofs] : 0;
        __syncthreads();
        sd[t] += u;
        __syncthreads();
    }
    if (t < nb) partials[t] = sd[t] - v;
}

__global__ void k_scan3(int* __restrict__ off, const int* __restrict__ partials,
                        int* __restrict__ cursor, int total) {
    int idx = blockIdx.x * blockDim.x + threadIdx.x;
    if (idx < total) {
        int v = off[idx] + partials[idx / SCAN_EPB];
        off[idx] = v;
        if (idx < total - 1) cursor[idx] = v;
    }
}

// scatter edges into CSR order: ONE 16B record per edge, 4 edges per thread
// rec = (a0, a1, a2, bits{src | maskbits<<16})   [src < 2^16]
__global__ void k_scatter(const int* __restrict__ ei, const float* __restrict__ attr,
                          const int* __restrict__ mt, const int* __restrict__ mg,
                          const int* __restrict__ mp, int E, int* __restrict__ cursor,
                          float4* __restrict__ rec) {
    int base = (blockIdx.x * blockDim.x + threadIdx.x) * 4;
    if (base >= E) return;
    if (base + 3 < E && (E & 3) == 0) {
        int4 d4 = *(const int4*)(ei + E + base);
        int4 s4 = *(const int4*)(ei + base);
        int4 t4 = *(const int4*)(mt + base);
        int4 g4 = *(const int4*)(mg + base);
        int4 p4 = *(const int4*)(mp + base);
        const float4* a4 = (const float4*)(attr + (size_t)base * 3);
        float4 a0 = a4[0], a1 = a4[1], a2 = a4[2]; // 12 floats = attrs of 4 edges
        // 4 independent atomics
        int p0 = atomicAdd(&cursor[d4.x], 1);
        int p1 = atomicAdd(&cursor[d4.y], 1);
        int p2 = atomicAdd(&cursor[d4.z], 1);
        int p3 = atomicAdd(&cursor[d4.w], 1);
        unsigned int b0 = (t4.x ? 1u : 0u) | (g4.x ? 2u : 0u) | (p4.x ? 4u : 0u);
        unsigned int b1 = (t4.y ? 1u : 0u) | (g4.y ? 2u : 0u) | (p4.y ? 4u : 0u);
        unsigned int b2 = (t4.z ? 1u : 0u) | (g4.z ? 2u : 0u) | (p4.z ? 4u : 0u);
        unsigned int b3 = (t4.w ? 1u : 0u) | (g4.w ? 2u : 0u) | (p4.w ? 4u : 0u);
        float4 r0 = make_float4(a0.x, a0.y, a0.z, __int_as_float((int)((unsigned)s4.x | (b0 << 16))));
        float4 r1 = make_float4(a0.w, a1.x, a1.y, __int_as_float((int)((unsigned)s4.y | (b1 << 16))));
        float4 r2 = make_float4(a1.z, a1.w, a2.x, __int_as_float((int)((unsigned)s4.z | (b2 << 16))));
        float4 r3 = make_float4(a2.y, a2.z, a2.w, __int_as_float((int)((unsigned)s4.w | (b3 << 16))));
        rec[p0] = r0; rec[p1] = r1; rec[p2] = r2; rec[p3] = r3;
    } else {
        for (int e = base; e < E && e < base + 4; ++e) {
            int d = ei[E + e];
            int p = atomicAdd(&cursor[d], 1);
            float4 r;
            r.x = attr[e * 3 + 0];
            r.y = attr[e * 3 + 1];
            r.z = attr[e * 3 + 2];
            unsigned int bits = (mt[e] != 0 ? 1u : 0u) | (mg[e] != 0 ? 2u : 0u) | (mp[e] != 0 ? 4u : 0u);
            r.w = __int_as_float((int)((unsigned)ei[e] | (bits << 16)));
            rec[p] = r;
        }
    }
}

// ------- branch GATs + fusion layer: 16 lanes per node -> h1[N,128] ---------
// side-product: writes csr_src[p] (unpacked from rec) for the downstream gatagg
__global__ void k_branch(const float* __restrict__ x, const int* __restrict__ off,
                         const float4* __restrict__ rec, int* __restrict__ csr_src,
                         const ConstBuf* __restrict__ cb, float* __restrict__ h1, int N) {
    __shared__ float sc[CB_FLOATS]; // ws|wd|M (60), G (1536), bias2 (128)
    for (int i = threadIdx.x; i < CB_FLOATS; i += 256) sc[i] = ((const float*)cb)[i];
    __syncthreads();
    int g = threadIdx.x >> 4, l = threadIdx.x & 15;
    int n = blockIdx.x * 16 + g;
    if (n >= N) return;

    float num[12], den[12], asum[9], cnt[3];
    #pragma unroll
    for (int i = 0; i < 12; ++i) { num[i] = 0.f; den[i] = 0.f; }
    #pragma unroll
    for (int i = 0; i < 9; ++i) asum[i] = 0.f;
    cnt[0] = cnt[1] = cnt[2] = 0.f;

    float xn = x[n];
    int beg = off[n], end = off[n + 1];
    for (int p = beg + l; p < end; p += 16) {
        float4 r = rec[p];
        unsigned int packed = (unsigned int)__float_as_int(r.w);
        int src = (int)(packed & 0xffffu);
        unsigned int bits = packed >> 16;
        csr_src[p] = src;
        float xs = x[src];
        float a0 = r.x, a1 = r.y, a2 = r.z;
        #pragma unroll
        for (int b = 0; b < 3; ++b) {
            if ((bits >> b) & 1u) {
                cnt[b] += 1.f;
                asum[b * 3 + 0] += a0; asum[b * 3 + 1] += a1; asum[b * 3 + 2] += a2;
                #pragma unroll
                for (int h = 0; h < 4; ++h) {
                    float al = xs * sc[b * 4 + h] + xn * sc[12 + b * 4 + h]
                             + a0 * sc[24 + b * 12 + 0 + h]
                             + a1 * sc[24 + b * 12 + 4 + h]
                             + a2 * sc[24 + b * 12 + 8 + h];
                    al = LEAKY(al);
                    float ex = __expf(al);
                    den[b * 4 + h] += ex;
                    num[b * 4 + h] += ex * xs;
                }
            }
        }
    }
    // butterfly reduce over the 16-lane group (masks <16 stay in-group)
    #pragma unroll
    for (int m = 1; m < 16; m <<= 1) {
        #pragma unroll
        for (int i = 0; i < 12; ++i) {
            num[i] += __shfl_xor(num[i], m, 64);
            den[i] += __shfl_xor(den[i], m, 64);
        }
        #pragma unroll
        for (int i = 0; i < 9; ++i) asum[i] += __shfl_xor(asum[i], m, 64);
        #pragma unroll
        for (int i = 0; i < 3; ++i) cnt[i] += __shfl_xor(cnt[i], m, 64);
    }
    // per-node softmax epilogue (computed redundantly on all 16 lanes)
    float S[12];
    #pragma unroll
    for (int b = 0; b < 3; ++b) {
        float inv = 1.f / fmaxf(cnt[b], 1.f);
        float l0 = asum[b * 3 + 0] * inv, l1 = asum[b * 3 + 1] * inv, l2 = asum[b * 3 + 2] * inv;
        #pragma unroll
        for (int h = 0; h < 4; ++h) {
            float lp = xn * (sc[b * 4 + h] + sc[12 + b * 4 + h])
                     + l0 * sc[24 + b * 12 + 0 + h]
                     + l1 * sc[24 + b * 12 + 4 + h]
                     + l2 * sc[24 + b * 12 + 8 + h];
            lp = LEAKY(lp);
            float exl = __expf(lp);
            float sden = den[b * 4 + h] + exl;
            S[b * 4 + h] = (num[b * 4 + h] + exl * xn) / sden;
        }
    }
    // fused h1 = relu(S @ G + bias2): each lane -> 8 columns
    int jb = l * 8;
    float o[8];
    #pragma unroll
    for (int q = 0; q < 8; ++q) {
        int j = jb + q;
        float a = sc[60 + 1536 + j];
        #pragma unroll
        for (int k = 0; k < 12; ++k) a += S[k] * sc[60 + k * 128 + j];
        o[q] = fmaxf(a, 0.f);
    }
    float4* dst = (float4*)(h1 + (size_t)n * 128 + jb);
    dst[0] = make_float4(o[0], o[1], o[2], o[3]);
    dst[1] = make_float4(o[4], o[5], o[6], o[7]);
}

// ---- MFMA [N,128]@[128,128]: A fp32 -> bf16, W pre-swizzled frags -> bf16 hx ----
// 256 threads = 4 waves; 64 nodes/block; wave w owns rows w*16..w*16+15.
__global__ void k_mm128b(const float* __restrict__ A, const unsigned short* __restrict__ wf,
                         unsigned short* __restrict__ hxb, int N) {
    __shared__ unsigned short sA[64 * 136]; // 272B padded rows -> conflict-free frag reads
    __shared__ unsigned short sW[16384];    // 32 KB fragment-layout W
    int tid = threadIdx.x;
    int base = blockIdx.x * 64;
    // stage W frags (coalesced 16B chunks)
    const float4* wf4 = (const float4*)wf;
    float4* sW4 = (float4*)sW;
    #pragma unroll
    for (int i = 0; i < 8; ++i) sW4[tid + i * 256] = wf4[tid + i * 256];
    // stage A rows as bf16 (coalesced float4 global reads)
    #pragma unroll
    for (int i = 0; i < 8; ++i) {
        int f = tid + i * 256;            // float4 index into 64x128 tile
        int row = f >> 5, c4 = f & 31;
        int n = base + row;
        float4 v = (n < N) ? ((const float4*)A)[(size_t)n * 32 + c4]
                           : make_float4(0.f, 0.f, 0.f, 0.f);
        us4 b;
        b.x = f_to_bf16(v.x); b.y = f_to_bf16(v.y);
        b.z = f_to_bf16(v.z); b.w = f_to_bf16(v.w);
        *(us4*)(&sA[row * 136 + c4 * 4]) = b;
    }
    __syncthreads();
    int wv = tid >> 6, lane = tid & 63;
    int q = lane >> 4, l15 = lane & 15;
    int rowbase = wv * 16;
    // A-frags: lane holds A[m=l15][k=q*8+j] per K-step
    s8 af[4];
    #pragma unroll
    for (int kk = 0; kk < 4; ++kk)
        af[kk] = *(const s8*)(&sA[(rowbase + l15) * 136 + kk * 32 + q * 8]);
    #pragma unroll
    for (int ct = 0; ct < 8; ++ct) {
        f4 acc = {0.f, 0.f, 0.f, 0.f};
        #pragma unroll
        for (int kk = 0; kk < 4; ++kk) {
            s8 bfr = *(const s8*)(&sW[((ct * 4 + kk) * 64 + lane) * 8]);
            acc = __builtin_amdgcn_mfma_f32_16x16x32_bf16(af[kk], bfr, acc, 0, 0, 0);
        }
        // D[row=q*4+r][col=l15] per verified C/D layout
        #pragma unroll
        for (int r = 0; r < 4; ++r) {
            int n = base + rowbase + q * 4 + r;
            if (n < N) hxb[(size_t)n * 128 + ct * 16 + l15] = f_to_bf16(acc[r]);
        }
    }
}

// ---- attention scores from bf16 hx table ----
__global__ void k_scoresb(const unsigned short* __restrict__ hxb, const float* __restrict__ a_s,
                          const float* __restrict__ a_d, float* __restrict__ as_,
                          float* __restrict__ ad_, int N) {
    __shared__ float sas[128], sad[128];
    if (threadIdx.x < 128) { sas[threadIdx.x] = a_s[threadIdx.x]; sad[threadIdx.x] = a_d[threadIdx.x]; }
    __syncthreads();
    int tid = blockIdx.x * blockDim.x + threadIdx.x;
    int n = tid >> 2, h = tid & 3;
    if (n >= N) return;
    const uint4* r4 = (const uint4*)(hxb + (size_t)n * 128 + h * 32);
    float ss = 0.f, sd2 = 0.f;
    #pragma unroll
    for (int c = 0; c < 4; ++c) {
        uint4 blob = r4[c];
        unsigned int us[4] = { blob.x, blob.y, blob.z, blob.w };
        #pragma unroll
        for (int q = 0; q < 4; ++q) {
            float2 v = bf2_to_f2(us[q]);
            int col = h * 32 + c * 8 + q * 2;
            ss  += v.x * sas[col] + v.y * sas[col + 1];
            sd2 += v.x * sad[col] + v.y * sad[col + 1];
        }
    }
    as_[(size_t)n * 4 + h] = ss;
    ad_[(size_t)n * 4 + h] = sd2;
}

// ------- GAT aggregation (conv2/conv3): wave per node, bf16 rows, 16-wide MLP -
__global__ void k_gatagg(const unsigned short* __restrict__ hxb, const float* __restrict__ as_,
                         const float* __restrict__ ad_, const float* __restrict__ b,
                         const int* __restrict__ off, const int* __restrict__ csr_src,
                         float* __restrict__ out, int N) {
    int wave = threadIdx.x >> 6, lane = threadIdx.x & 63;
    int n = blockIdx.x * 4 + wave;
    if (n >= N) return;
    int h = lane >> 4;
    int lofs = lane * 2;
    float adn = ad_[(size_t)n * 4 + h];
    int beg = off[n], end = off[n + 1];
    float acc0 = 0.f, acc1 = 0.f, accd = 0.f;
    for (int p = beg; p < end; p += 16) {
        int s[16]; float e[16]; unsigned int u[16]; bool valid[16];
        #pragma unroll
        for (int i = 0; i < 16; ++i) {
            valid[i] = (p + i < end);
            int q = valid[i] ? (p + i) : beg;
            s[i] = csr_src[q];
        }
        #pragma unroll
        for (int i = 0; i < 16; ++i) e[i] = as_[(size_t)s[i] * 4 + h];
        #pragma unroll
        for (int i = 0; i < 16; ++i) u[i] = *(const unsigned int*)(hxb + (size_t)s[i] * 128 + lofs);
        #pragma unroll
        for (int i = 0; i < 16; ++i) {
            float ex = valid[i] ? __expf(LEAKY(e[i] + adn)) : 0.f;
            float2 v = bf2_to_f2(u[i]);
            acc0 += ex * v.x; acc1 += ex * v.y; accd += ex;
        }
    }
    float aln = LEAKY(as_[(size_t)n * 4 + h] + adn);
    float exl = __expf(aln);
    unsigned int un = *(const unsigned int*)(hxb + (size_t)n * 128 + lofs);
    float2 vn = bf2_to_f2(un);
    float inv = 1.f / (accd + exl);
    float o0 = (acc0 + exl * vn.x) * inv + b[lofs + 0];
    float o1 = (acc1 + exl * vn.y) * inv + b[lofs + 1];
    float2 r; r.x = fmaxf(o0, 0.f); r.y = fmaxf(o1, 0.f);
    *(float2*)(out + (size_t)n * 128 + lofs) = r;
}

// ------- classifier + log_softmax: wave = 8 nodes x 64 cols, Wc1 from L1 -----
#define CLS_NPB 32
__global__ void k_cls(const float* __restrict__ h3, const float* __restrict__ Wc1,
                      const float* __restrict__ bc1, const float* __restrict__ Wc2,
                      const float* __restrict__ bc2, float* __restrict__ out, int N) {
    __shared__ float hs[CLS_NPB * 128]; // 16 KB
    int tid = threadIdx.x;
    int nb = blockIdx.x * CLS_NPB;
    for (int i = tid; i < CLS_NPB * 128; i += 256) {
        int n = nb + (i >> 7);
        hs[i] = (n < N) ? h3[(size_t)n * 128 + (i & 127)] : 0.f;
    }
    __syncthreads();
    int g = tid >> 6, j = tid & 63;
    const float4* hb4 = (const float4*)(hs + g * 8 * 128);
    float bj = bc1[j];
    float acc[8];
    #pragma unroll
    for (int i = 0; i < 8; ++i) acc[i] = bj;
    for (int k = 0; k < 128; k += 4) {
        float w0 = Wc1[(k + 0) * 64 + j];
        float w1 = Wc1[(k + 1) * 64 + j];
        float w2 = Wc1[(k + 2) * 64 + j];
        float w3 = Wc1[(k + 3) * 64 + j];
        #pragma unroll
        for (int i = 0; i < 8; ++i) {
            float4 h4 = hb4[(i * 128 + k) >> 2];
            acc[i] += h4.x * w0 + h4.y * w1 + h4.z * w2 + h4.w * w3;
        }
    }
    float w2v[5];
    #pragma unroll
    for (int c = 0; c < 5; ++c) w2v[c] = Wc2[j * 5 + c];
    #pragma unroll
    for (int i = 0; i < 8; ++i) {
        float t = fmaxf(acc[i], 0.f);
        float p[5];
        #pragma unroll
        for (int c = 0; c < 5; ++c) p[c] = t * w2v[c];
        #pragma unroll
        for (int m = 1; m < 64; m <<= 1) {
            #pragma unroll
            for (int c = 0; c < 5; ++c) p[c] += __shfl_xor(p[c], m, 64);
        }
        if (j == 0) {
            int n = nb + g * 8 + i;
            if (n < N) {
                float l[5], mx = -1e30f;
                #pragma unroll
                for (int c = 0; c < 5; ++c) { l[c] = p[c] + bc2[c]; mx = fmaxf(mx, l[c]); }
                float s = 0.f;
                #pragma unroll
                for (int c = 0; c < 5; ++c) s += __expf(l[c] - mx);
                float lse = mx + __logf(s);
                #pragma unroll
                for (int c = 0; c < 5; ++c) out[(size_t)n * 5 + c] = l[c] - lse;
            }
        }
    }
}

extern "C" void kernel_launch(void* const* d_in, const int* in_sizes, int n_in,
                              void* d_out, int out_size, void* d_ws, size_t ws_size,
                              hipStream_t stream) {
    const float* x    = (const float*)d_in[0];
    const int*   ei   = (const int*)d_in[1];
    const float* attr = (const float*)d_in[2];
    const int*   mt   = (const int*)d_in[3];
    const int*   mg   = (const int*)d_in[4];
    const int*   mp   = (const int*)d_in[5];
    const float* Wf   = (const float*)d_in[24];
    const float* bf   = (const float*)d_in[25];
    const float* W2   = (const float*)d_in[26];
    const float* a2s  = (const float*)d_in[27];
    const float* a2d  = (const float*)d_in[28];
    const float* b2   = (const float*)d_in[29];
    const float* W3   = (const float*)d_in[30];
    const float* a3s  = (const float*)d_in[31];
    const float* a3d  = (const float*)d_in[32];
    const float* b3   = (const float*)d_in[33];
    const float* Wc1  = (const float*)d_in[34];
    const float* bc1  = (const float*)d_in[35];
    const float* Wc2  = (const float*)d_in[36];
    const float* bc2  = (const float*)d_in[37];

    int N = in_sizes[0];
    int E = in_sizes[1] / 2;

    char* w = (char*)d_ws;
    auto alloc = [&](size_t bytes) {
        char* p = w;
        w += (bytes + 255) & ~(size_t)255;
        return p;
    };
    int* off      = (int*)alloc((size_t)(N + 1) * 4);
    int* cursor   = (int*)alloc((size_t)N * 4);
    int* deg      = (int*)alloc((size_t)N * 4);
    int* partials = (int*)alloc(1024 * 4);
    int* csr_src  = (int*)alloc((size_t)E * 4);
    ConstBuf* cb  = (ConstBuf*)alloc(sizeof(ConstBuf));
    float* as_    = (float*)alloc((size_t)N * 4 * 4);
    float* ad_    = (float*)alloc((size_t)N * 4 * 4);
    float* bufA   = (float*)alloc((size_t)N * 128 * 4);
    float4* rec   = (float4*)alloc((size_t)E * 16);
    unsigned short* hxb = (unsigned short*)alloc((size_t)N * 256);
    unsigned short* wf2 = (unsigned short*)alloc(16384 * 2);
    unsigned short* wf3 = (unsigned short*)alloc(16384 * 2);

    PreArgs pa;
    for (int b = 0; b < 3; ++b) {
        pa.br[b].W   = (const float*)d_in[6 + b * 6 + 0];
        pa.br[b].as_ = (const float*)d_in[6 + b * 6 + 1];
        pa.br[b].ad_ = (const float*)d_in[6 + b * 6 + 2];
        pa.br[b].ae  = (const float*)d_in[6 + b * 6 + 3];
        pa.br[b].We  = (const float*)d_in[6 + b * 6 + 4];
        pa.br[b].b   = (const float*)d_in[6 + b * 6 + 5];
    }
    pa.Wf = Wf; pa.bf = bf; pa.cb = cb;

    int total = N + 1;
    int nScanBlocks = (total + SCAN_EPB - 1) / SCAN_EPB;

    hipMemsetAsync(deg, 0, (size_t)N * 4, stream);
    hipLaunchKernelGGL(k_pre_all, dim3(3), dim3(256), 0, stream, pa, W2, wf2, W3, wf3);
    int gE4 = (E + 1023) / 1024;
    hipLaunchKernelGGL(k_count, dim3(gE4), dim3(256), 0, stream, ei, E, deg);
    hipLaunchKernelGGL(k_scan1, dim3(nScanBlocks), dim3(256), 0, stream, deg, off, partials, total);
    hipLaunchKernelGGL(k_scan2, dim3(1), dim3(256), 0, stream, partials, nScanBlocks);
    hipLaunchKernelGGL(k_scan3, dim3((total + 255) / 256), dim3(256), 0, stream,
                       off, partials, cursor, total);
    hipLaunchKernelGGL(k_scatter, dim3(gE4), dim3(256), 0, stream,
                       ei, attr, mt, mg, mp, E, cursor, rec);
    hipLaunchKernelGGL(k_branch, dim3((N + 15) / 16), dim3(256), 0, stream,
                       x, off, rec, csr_src, cb, bufA, N);
    // conv2
    hipLaunchKernelGGL(k_mm128b, dim3((N + 63) / 64), dim3(256), 0, stream,
                       bufA, wf2, hxb, N);
    hipLaunchKernelGGL(k_scoresb, dim3(((size_t)N * 4 + 255) / 256), dim3(256), 0, stream,
                       hxb, a2s, a2d, as_, ad_, N);
    hipLaunchKernelGGL(k_gatagg, dim3((N + 3) / 4), dim3(256), 0, stream,
                       hxb, as_, ad_, b2, off, csr_src, bufA, N);
    // conv3
    hipLaunchKernelGGL(k_mm128b, dim3((N + 63) / 64), dim3(256), 0, stream,
                       bufA, wf3, hxb, N);
    hipLaunchKernelGGL(k_scoresb, dim3(((size_t)N * 4 + 255) / 256), dim3(256), 0, stream,
                       hxb, a3s, a3d, as_, ad_, N);
    hipLaunchKernelGGL(k_gatagg, dim3((N + 3) / 4), dim3(256), 0, stream,
                       hxb, as_, ad_, b3, off, csr_src, bufA, N);
    // classifier
    hipLaunchKernelGGL(k_cls, dim3((N + CLS_NPB - 1) / CLS_NPB), dim3(256), 0, stream,
                       bufA, Wc1, bc1, Wc2, bc2, (float*)d_out, N);
}